// Round 5
// baseline (1895.357 us; speedup 1.0000x reference)
//
#include <hip/hip_runtime.h>

typedef __bf16 bf16_t;
typedef __attribute__((ext_vector_type(8))) __bf16 bf16x8;
typedef __attribute__((ext_vector_type(4))) float floatx4;

#define T_SEQ 2048
#define HID 3584
#define NH 28
#define NKV 4
#define HD 128
#define GQA 7
#define SCALE_F 0.08838834764831845f

// ---------------- input dtype detector ----------------
// Samples even halfwords of hidden_states. fp32 buffer -> those are low-mantissa
// bits (uniform) -> ~25% have bf16-exponent >= 0xC0 (|x| >= 2^65, impossible for
// unit-scale data). Genuine bf16 -> 0 hits. *flag > 32 <=> inputs are fp32.
__global__ void detect_k(const unsigned short* __restrict__ h, int* __restrict__ flag) {
  int cnt = 0;
  for (int j = threadIdx.x * 2; j < 2048; j += 512) {
    const unsigned short u = h[j];
    const int e = (u >> 7) & 0xFF;
    if (e >= 0xC0) cnt++;
  }
  if (cnt) atomicAdd(flag, cnt);
}

// load 8 contiguous elements as bf16x8, converting from fp32 if f32 is set
__device__ __forceinline__ bf16x8 ld8(const void* p, long idx, bool f32) {
  if (f32) {
    const float* q = (const float*)p + idx;
    const floatx4 u = *(const floatx4*)q;
    const floatx4 v = *(const floatx4*)(q + 4);
    bf16x8 r;
    r[0] = (bf16_t)u[0]; r[1] = (bf16_t)u[1]; r[2] = (bf16_t)u[2]; r[3] = (bf16_t)u[3];
    r[4] = (bf16_t)v[0]; r[5] = (bf16_t)v[1]; r[6] = (bf16_t)v[2]; r[7] = (bf16_t)v[3];
    return r;
  }
  return *(const bf16x8*)((const bf16_t*)p + idx);
}

// ---------------- GEMM: C[M][N] = A[M][K] @ B[K][N] (+bias) ----------------
// 128x128 tile, BK=32, 256 threads (4 waves, 2x2 of 64x64 wave tiles), mfma 16x16x32 bf16.
// A/B natural layout, optionally fp32 (aMode/bMode: 1 = fp32 if *flag>32).
// B-tile transposed into LDS during staging (k-pairs in u32, XOR-swizzled).
// transC=1: write bf16 C transposed C[n*ldc+m]. c32=1: write fp32 C (non-trans).
__global__ __launch_bounds__(256) void gemm_nt_k(
    const void* A, long lda, const void* B, long ldb,
    const void* bias, void* Cv, long ldc,
    int K, int aMode, int bMode, int transC, int c32, const int* flag) {
  __shared__ alignas(16) bf16_t ldsA[128 * 32];          // [m][k]
  __shared__ alignas(16) unsigned int ldsB32[128 * 16];  // [n][kpair] swizzled
  const int f = *flag;
  const bool aF32 = aMode && (f > 32);
  const bool bF32 = bMode && (f > 32);
  const int tid = threadIdx.x;
  const int lane = tid & 63;
  const int w = tid >> 6;
  const int wr = w >> 1, wc = w & 1;
  const int col = lane & 15, quad = lane >> 4;
  const long m0 = (long)blockIdx.y * 128, n0 = (long)blockIdx.x * 128;

  const int ar1 = tid >> 2, ak = (tid & 3) * 8;
  const int ar2 = 64 + ar1;
  const int kk = (tid >> 4) * 2;
  const int nn = (tid & 15) * 8;
  const int kp = kk >> 1;

  floatx4 acc[4][4] = {};

  for (int k0 = 0; k0 < K; k0 += 32) {
    const bf16x8 a1 = ld8(A, (m0 + ar1) * lda + k0 + ak, aF32);
    const bf16x8 a2 = ld8(A, (m0 + ar2) * lda + k0 + ak, aF32);
    const bf16x8 b0 = ld8(B, (long)(k0 + kk) * ldb + n0 + nn, bF32);
    const bf16x8 b1 = ld8(B, (long)(k0 + kk + 1) * ldb + n0 + nn, bF32);
    __syncthreads();  // previous iteration's fragment reads complete
    *(bf16x8*)(ldsA + ar1 * 32 + ak) = a1;
    *(bf16x8*)(ldsA + ar2 * 32 + ak) = a2;
#pragma unroll
    for (int j = 0; j < 8; ++j) {
      const int n = nn + j;
      const int pk = ((((kp >> 2) ^ ((n >> 3) & 3)) << 2) | (kp & 3));
      union { struct { bf16_t lo, hi; } s; unsigned int u; } cv;
      cv.s.lo = b0[j];
      cv.s.hi = b1[j];
      ldsB32[n * 16 + pk] = cv.u;
    }
    __syncthreads();
    bf16x8 af[4], bfv[4];
#pragma unroll
    for (int i = 0; i < 4; ++i)
      af[i] = *(const bf16x8*)(ldsA + (wr * 64 + i * 16 + col) * 32 + quad * 8);
#pragma unroll
    for (int j = 0; j < 4; ++j) {
      const int n = wc * 64 + j * 16 + col;
      const int blk = quad ^ ((n >> 3) & 3);
      bfv[j] = *(const bf16x8*)((const bf16_t*)(ldsB32 + n * 16 + blk * 4));
    }
#pragma unroll
    for (int i = 0; i < 4; ++i)
#pragma unroll
      for (int jj = 0; jj < 4; ++jj)
        acc[i][jj] = __builtin_amdgcn_mfma_f32_16x16x32_bf16(af[i], bfv[jj], acc[i][jj], 0, 0, 0);
  }

#pragma unroll
  for (int i = 0; i < 4; ++i) {
#pragma unroll
    for (int j = 0; j < 4; ++j) {
      const long row0 = m0 + wr * 64 + i * 16 + quad * 4;
      const long cc = n0 + wc * 64 + j * 16 + col;
      const float bvv = bias ? (bF32 ? ((const float*)bias)[cc]
                                     : (float)((const bf16_t*)bias)[cc])
                             : 0.f;
#pragma unroll
      for (int r = 0; r < 4; ++r) {
        const float v = acc[i][j][r] + bvv;
        if (transC)      ((bf16_t*)Cv)[cc * ldc + (row0 + r)] = (bf16_t)v;
        else if (c32)    ((float*)Cv)[(row0 + r) * ldc + cc] = v;
        else             ((bf16_t*)Cv)[(row0 + r) * ldc + cc] = (bf16_t)v;
      }
    }
  }
}

// ---------------- RoPE in-place: buf [T][ld] bf16, heads at h*128, pairs (d, d+64) ----------------
__global__ void rope_k(bf16_t* buf, const int* __restrict__ pos, long ld, int nheads) {
  const int idx = blockIdx.x * 256 + threadIdx.x;
  const int total = T_SEQ * nheads * 64;
  if (idx >= total) return;
  const int d = idx & 63;
  const int th = idx >> 6;
  const int h = th % nheads;
  const int t = th / nheads;
  const float inv = exp2f((float)d * (-19.931568569324174f / 64.f));
  const float ang = (float)pos[t] * inv;
  float sn, cs;
  __sincosf(ang, &sn, &cs);
  bf16_t* p = buf + (long)t * ld + h * HD + d;
  const float x1 = (float)p[0];
  const float x2 = (float)p[64];
  p[0] = (bf16_t)(x1 * cs - x2 * sn);
  p[64] = (bf16_t)(x2 * cs + x1 * sn);
}

// ---------------- flash attention ----------------
// grid (32 q-tiles of 64 rows, 28 heads), block 256 = 4 waves x 16 q-rows each.
__global__ __launch_bounds__(256) void attn_k(
    const bf16_t* __restrict__ q, long qs,
    const bf16_t* __restrict__ k, long ks,
    const bf16_t* __restrict__ vt,  // [512][2048] (hkv*128+d major, s minor)
    bf16_t* __restrict__ out, long os) {
  __shared__ alignas(16) bf16_t pbuf[4][16 * 32];
  const int h = blockIdx.y;
  const int hkv = h / GQA;
  const int tid = threadIdx.x;
  const int lane = tid & 63;
  const int w = tid >> 6;
  const int col = lane & 15, quad = lane >> 4;
  const int t0 = blockIdx.x * 64 + w * 16;

  bf16x8 aq[4];
  {
    const bf16_t* qp = q + (long)(t0 + col) * qs + h * HD + quad * 8;
#pragma unroll
    for (int c = 0; c < 4; ++c) aq[c] = *(const bf16x8*)(qp + c * 32);
  }

  floatx4 O[8] = {};
  float m_i[4], l_i[4];
#pragma unroll
  for (int r = 0; r < 4; ++r) { m_i[r] = -1e30f; l_i[r] = 0.f; }

  for (int s0 = 0; s0 < T_SEQ; s0 += 32) {
    floatx4 S[2] = {};
#pragma unroll
    for (int nt = 0; nt < 2; ++nt) {
      const bf16_t* kpp = k + (long)(s0 + nt * 16 + col) * ks + hkv * HD + quad * 8;
#pragma unroll
      for (int c = 0; c < 4; ++c) {
        const bf16x8 bk = *(const bf16x8*)(kpp + c * 32);
        S[nt] = __builtin_amdgcn_mfma_f32_16x16x32_bf16(aq[c], bk, S[nt], 0, 0, 0);
      }
    }
    float P0[4], P1[4], alpha[4];
#pragma unroll
    for (int r = 0; r < 4; ++r) {
      const float sv0 = S[0][r] * SCALE_F;
      const float sv1 = S[1][r] * SCALE_F;
      float mx = fmaxf(sv0, sv1);
#pragma unroll
      for (int off = 1; off < 16; off <<= 1)
        mx = fmaxf(mx, __shfl_xor(mx, off, 64));
      const float mnew = fmaxf(m_i[r], mx);
      alpha[r] = __expf(m_i[r] - mnew);
      const float p0 = __expf(sv0 - mnew);
      const float p1 = __expf(sv1 - mnew);
      float rs = p0 + p1;
#pragma unroll
      for (int off = 1; off < 16; off <<= 1)
        rs += __shfl_xor(rs, off, 64);
      l_i[r] = l_i[r] * alpha[r] + rs;
      m_i[r] = mnew;
      P0[r] = p0; P1[r] = p1;
    }
#pragma unroll
    for (int dt = 0; dt < 8; ++dt)
#pragma unroll
      for (int r = 0; r < 4; ++r)
        O[dt][r] *= alpha[r];
#pragma unroll
    for (int r = 0; r < 4; ++r) {
      pbuf[w][(quad * 4 + r) * 32 + col] = (bf16_t)P0[r];
      pbuf[w][(quad * 4 + r) * 32 + 16 + col] = (bf16_t)P1[r];
    }
    __syncthreads();
    const bf16x8 pa = *(const bf16x8*)(&pbuf[w][col * 32 + quad * 8]);
#pragma unroll
    for (int dt = 0; dt < 8; ++dt) {
      const bf16x8 bv = *(const bf16x8*)(vt + (long)(hkv * HD + dt * 16 + col) * T_SEQ + s0 + quad * 8);
      O[dt] = __builtin_amdgcn_mfma_f32_16x16x32_bf16(pa, bv, O[dt], 0, 0, 0);
    }
  }

#pragma unroll
  for (int r = 0; r < 4; ++r) l_i[r] = 1.f / l_i[r];
#pragma unroll
  for (int dt = 0; dt < 8; ++dt) {
#pragma unroll
    for (int r = 0; r < 4; ++r) {
      const long trow = t0 + quad * 4 + r;
      out[trow * os + h * HD + dt * 16 + col] = (bf16_t)(O[dt][r] * l_i[r]);
    }
  }
}

extern "C" void kernel_launch(void* const* d_in, const int* in_sizes, int n_in,
                              void* d_out_v, int out_size, void* d_ws, size_t ws_size,
                              hipStream_t stream) {
  const int* pos = (const int*)d_in[0];
  const void* hidden = d_in[1];
  const void* wq = d_in[2];
  const void* bq = d_in[3];
  const void* wk = d_in[4];
  const void* bk = d_in[5];
  const void* wv = d_in[6];
  const void* bv = d_in[7];
  const void* wo = d_in[8];

  // d_out capacity (fp32 out): 2048*3584*4 = 29,360,128 B.
  //   lower half  [0, 14,680,064)        : q bf16 [2048][3584]
  //   upper half  [14,680,064, 29.36MB)  : attn bf16 [2048][3584]
  //   final fp32 output overwrites everything (3 stream-ordered slices).
  bf16_t* qbuf = (bf16_t*)d_out_v;
  bf16_t* attnb = (bf16_t*)d_out_v + (size_t)T_SEQ * HID;
  float* outf = (float*)d_out_v;

  // ---- workspace (needs 4,194,308 B) ----
  //  [0, 2 MiB)      kbuf [2048][512] bf16
  //  [2 MiB, 4 MiB)  vt   [512][2048] bf16  (written transposed by V-GEMM)
  //  [0, 3.67 MB)    acopy [512][3584] bf16 (attn rows 1536..2047; after attention)
  //  [4 MiB, +4)     dtype flag (int)
  char* ws = (char*)d_ws;
  bf16_t* kbuf = (bf16_t*)ws;
  bf16_t* vt = (bf16_t*)(ws + 2097152);
  bf16_t* acopy = (bf16_t*)ws;
  int* flag = (int*)(ws + 4194304);

  hipMemsetAsync(flag, 0, 4, stream);
  detect_k<<<1, 256, 0, stream>>>((const unsigned short*)hidden, flag);

  // q = hidden @ wq + bq -> qbuf [2048][3584] bf16
  gemm_nt_k<<<dim3(28, 16), 256, 0, stream>>>(hidden, HID, wq, HID, bq, qbuf, HID,
                                              HID, 1, 1, 0, 0, flag);
  // k = hidden @ wk + bk -> kbuf [2048][512] bf16
  gemm_nt_k<<<dim3(4, 16), 256, 0, stream>>>(hidden, HID, wk, 512, bk, kbuf, 512,
                                             HID, 1, 1, 0, 0, flag);
  // v = hidden @ wv + bv -> vt [512][2048] bf16 (transposed write)
  gemm_nt_k<<<dim3(4, 16), 256, 0, stream>>>(hidden, HID, wv, 512, bv, vt, T_SEQ,
                                             HID, 1, 1, 1, 0, flag);

  // RoPE in-place
  rope_k<<<(T_SEQ * NH * 64) / 256, 256, 0, stream>>>(qbuf, pos, HID, NH);
  rope_k<<<(T_SEQ * NKV * 64) / 256, 256, 0, stream>>>(kbuf, pos, 512, NKV);

  // flash attention: q (lower half) -> attnb (upper half)
  attn_k<<<dim3(32, 28), 256, 0, stream>>>(qbuf, HID, kbuf, 512, vt, attnb, HID);

  // save attn rows 1536..2047 (their bytes get overwritten by out-proj slice 3)
  hipMemcpyAsync(acopy, attnb + (size_t)1536 * HID, (size_t)512 * HID * 2,
                 hipMemcpyDeviceToDevice, stream);

  // out-projection, fp32 output, 3 race-free stream-ordered slices:
  // rows [0,1024): writes fp32 bytes [0,14.68M) -- disjoint from all attn bytes
  gemm_nt_k<<<dim3(28, 8), 256, 0, stream>>>(attnb, HID, wo, HID, nullptr,
                                             outf, HID, HID, 0, 1, 0, 1, flag);
  // rows [1024,1536): writes [14.68M,22.02M) = dead attn rows 0..1023; reads rows 1024..1535
  gemm_nt_k<<<dim3(28, 4), 256, 0, stream>>>(attnb + (size_t)1024 * HID, HID, wo, HID,
                                             nullptr, outf + (size_t)1024 * HID, HID,
                                             HID, 0, 1, 0, 1, flag);
  // rows [1536,2048): reads the ws copy; writes [22.02M,29.36M) (attn rows 1024+ dead)
  gemm_nt_k<<<dim3(28, 4), 256, 0, stream>>>(acopy, HID, wo, HID,
                                             nullptr, outf + (size_t)1536 * HID, HID,
                                             HID, 0, 1, 0, 1, flag);
}

// Round 6
// 1059.969 us; speedup vs baseline: 1.7881x; 1.7881x over previous
//
#include <hip/hip_runtime.h>

typedef __bf16 bf16_t;
typedef __attribute__((ext_vector_type(8))) __bf16 bf16x8;
typedef __attribute__((ext_vector_type(4))) float floatx4;

#define T_SEQ 2048
#define HID 3584
#define NH 28
#define NKV 4
#define HD 128
#define GQA 7
#define SCALE_F 0.08838834764831845f

// ---------------- fp32 -> bf16 conversion (n % 2048 == 0) ----------------
__global__ void conv_bf_k(const float* __restrict__ src, bf16_t* __restrict__ dst, long n) {
  const long i = ((long)blockIdx.x * 256 + threadIdx.x) * 8;
  if (i >= n) return;
  const floatx4 a = *(const floatx4*)(src + i);
  const floatx4 b = *(const floatx4*)(src + i + 4);
  bf16x8 r;
  r[0] = (bf16_t)a[0]; r[1] = (bf16_t)a[1]; r[2] = (bf16_t)a[2]; r[3] = (bf16_t)a[3];
  r[4] = (bf16_t)b[0]; r[5] = (bf16_t)b[1]; r[6] = (bf16_t)b[2]; r[7] = (bf16_t)b[3];
  *(bf16x8*)(dst + i) = r;
}

// load 8 contiguous elements as bf16x8, converting from fp32 if f32 is set
__device__ __forceinline__ bf16x8 ld8(const void* p, long idx, bool f32) {
  if (f32) {
    const float* q = (const float*)p + idx;
    const floatx4 u = *(const floatx4*)q;
    const floatx4 v = *(const floatx4*)(q + 4);
    bf16x8 r;
    r[0] = (bf16_t)u[0]; r[1] = (bf16_t)u[1]; r[2] = (bf16_t)u[2]; r[3] = (bf16_t)u[3];
    r[4] = (bf16_t)v[0]; r[5] = (bf16_t)v[1]; r[6] = (bf16_t)v[2]; r[7] = (bf16_t)v[3];
    return r;
  }
  return *(const bf16x8*)((const bf16_t*)p + idx);
}

// ---------------- GEMM: C[M][N] = A[M][K] @ B[K][N] (+fp32 bias) ----------------
// 128x128 tile, BK=32, 256 threads, mfma 16x16x32 bf16. A/B natural layout,
// optionally fp32 (aMode/bMode=1: fp32 if *flag>32). B-tile transposed into LDS
// during staging (k-pairs in u32, XOR-swizzled). transC=1: bf16 C transposed
// C[n*ldc+m]. c32=1: fp32 C. [HW-validated end-to-end in R5]
__global__ __launch_bounds__(256) void gemm_nt_k(
    const void* A, long lda, const void* B, long ldb,
    const float* bias, void* Cv, long ldc,
    int K, int aMode, int bMode, int transC, int c32, const int* flag) {
  __shared__ alignas(16) bf16_t ldsA[128 * 32];          // [m][k]
  __shared__ alignas(16) unsigned int ldsB32[128 * 16];  // [n][kpair] swizzled
  const int f = *flag;
  const bool aF32 = aMode && (f > 32);
  const bool bF32 = bMode && (f > 32);
  const int tid = threadIdx.x;
  const int lane = tid & 63;
  const int w = tid >> 6;
  const int wr = w >> 1, wc = w & 1;
  const int col = lane & 15, quad = lane >> 4;
  const long m0 = (long)blockIdx.y * 128, n0 = (long)blockIdx.x * 128;

  const int ar1 = tid >> 2, ak = (tid & 3) * 8;
  const int ar2 = 64 + ar1;
  const int kk = (tid >> 4) * 2;
  const int nn = (tid & 15) * 8;
  const int kp = kk >> 1;

  floatx4 acc[4][4] = {};

  for (int k0 = 0; k0 < K; k0 += 32) {
    const bf16x8 a1 = ld8(A, (m0 + ar1) * lda + k0 + ak, aF32);
    const bf16x8 a2 = ld8(A, (m0 + ar2) * lda + k0 + ak, aF32);
    const bf16x8 b0 = ld8(B, (long)(k0 + kk) * ldb + n0 + nn, bF32);
    const bf16x8 b1 = ld8(B, (long)(k0 + kk + 1) * ldb + n0 + nn, bF32);
    __syncthreads();
    *(bf16x8*)(ldsA + ar1 * 32 + ak) = a1;
    *(bf16x8*)(ldsA + ar2 * 32 + ak) = a2;
#pragma unroll
    for (int j = 0; j < 8; ++j) {
      const int n = nn + j;
      const int pk = ((((kp >> 2) ^ ((n >> 3) & 3)) << 2) | (kp & 3));
      union { struct { bf16_t lo, hi; } s; unsigned int u; } cv;
      cv.s.lo = b0[j];
      cv.s.hi = b1[j];
      ldsB32[n * 16 + pk] = cv.u;
    }
    __syncthreads();
    bf16x8 af[4], bfv[4];
#pragma unroll
    for (int i = 0; i < 4; ++i)
      af[i] = *(const bf16x8*)(ldsA + (wr * 64 + i * 16 + col) * 32 + quad * 8);
#pragma unroll
    for (int j = 0; j < 4; ++j) {
      const int n = wc * 64 + j * 16 + col;
      const int blk = quad ^ ((n >> 3) & 3);
      bfv[j] = *(const bf16x8*)((const bf16_t*)(ldsB32 + n * 16 + blk * 4));
    }
#pragma unroll
    for (int i = 0; i < 4; ++i)
#pragma unroll
      for (int jj = 0; jj < 4; ++jj)
        acc[i][jj] = __builtin_amdgcn_mfma_f32_16x16x32_bf16(af[i], bfv[jj], acc[i][jj], 0, 0, 0);
  }

#pragma unroll
  for (int i = 0; i < 4; ++i) {
#pragma unroll
    for (int j = 0; j < 4; ++j) {
      const long row0 = m0 + wr * 64 + i * 16 + quad * 4;
      const long cc = n0 + wc * 64 + j * 16 + col;
      const float bvv = bias ? bias[cc] : 0.f;
#pragma unroll
      for (int r = 0; r < 4; ++r) {
        const float v = acc[i][j][r] + bvv;
        if (transC)   ((bf16_t*)Cv)[cc * ldc + (row0 + r)] = (bf16_t)v;
        else if (c32) ((float*)Cv)[(row0 + r) * ldc + cc] = v;
        else          ((bf16_t*)Cv)[(row0 + r) * ldc + cc] = (bf16_t)v;
      }
    }
  }
}

// ---------------- RoPE in-place: buf [T][ld] bf16 ----------------
__global__ void rope_k(bf16_t* buf, const int* __restrict__ pos, long ld, int nheads) {
  const int idx = blockIdx.x * 256 + threadIdx.x;
  const int total = T_SEQ * nheads * 64;
  if (idx >= total) return;
  const int d = idx & 63;
  const int th = idx >> 6;
  const int h = th % nheads;
  const int t = th / nheads;
  const float inv = exp2f((float)d * (-19.931568569324174f / 64.f));
  const float ang = (float)pos[t] * inv;
  float sn, cs;
  __sincosf(ang, &sn, &cs);
  bf16_t* p = buf + (long)t * ld + h * HD + d;
  const float x1 = (float)p[0];
  const float x2 = (float)p[64];
  p[0] = (bf16_t)(x1 * cs - x2 * sn);
  p[64] = (bf16_t)(x2 * cs + x1 * sn);
}

// ---------------- flash attention v2 ----------------
// grid (32, 28), block 256 = 4 waves x 16 q-rows. s-tile = 128. NO barriers:
// pbuf is per-wave; ds_write->ds_read ordering within a wave is enforced by
// compiler lgkmcnt waits. pbuf layout XOR-swizzled: elem (m,k) at
// m*128 + ((k>>3)^m)*8 + (k&7)  -> conflict-floor b128 reads, 4-way writes.
__global__ __launch_bounds__(256) void attn2_k(
    const bf16_t* q, long qs,
    const bf16_t* __restrict__ k, long ks,
    const bf16_t* __restrict__ vt,  // [512][2048] (hkv*128+d major, s minor)
    bf16_t* out, long os) {
  __shared__ alignas(16) bf16_t pbuf[4][16 * 128];
  const int h = blockIdx.y;
  const int hkvHD = (h / GQA) * HD;
  const int tid = threadIdx.x;
  const int lane = tid & 63;
  const int w = tid >> 6;
  const int col = lane & 15, quad = lane >> 4;
  const int t0 = blockIdx.x * 64 + w * 16;

  bf16x8 aq[4];
  {
    const bf16_t* qp = q + (long)(t0 + col) * qs + h * HD + quad * 8;
#pragma unroll
    for (int c = 0; c < 4; ++c) {
      aq[c] = *(const bf16x8*)(qp + c * 32);
#pragma unroll
      for (int e = 0; e < 8; ++e) aq[c][e] = (bf16_t)((float)aq[c][e] * SCALE_F);
    }
  }

  floatx4 O[8] = {};
  float m_i[4], l_i[4];
#pragma unroll
  for (int r = 0; r < 4; ++r) { m_i[r] = -1e30f; l_i[r] = 0.f; }

  for (int s0 = 0; s0 < T_SEQ; s0 += 128) {
    // S = q . K^T for 128 s-cols (8 n-tiles)
    floatx4 S[8] = {};
#pragma unroll
    for (int nt = 0; nt < 8; ++nt) {
      const bf16_t* kpp = k + (long)(s0 + nt * 16 + col) * ks + hkvHD + quad * 8;
#pragma unroll
      for (int c = 0; c < 4; ++c) {
        const bf16x8 bk = *(const bf16x8*)(kpp + c * 32);
        S[nt] = __builtin_amdgcn_mfma_f32_16x16x32_bf16(aq[c], bk, S[nt], 0, 0, 0);
      }
    }
    // online softmax per row m = quad*4+r, 128 cols spread as 8 regs x 16 lanes
    float alpha[4];
#pragma unroll
    for (int r = 0; r < 4; ++r) {
      float mx = S[0][r];
#pragma unroll
      for (int nt = 1; nt < 8; ++nt) mx = fmaxf(mx, S[nt][r]);
#pragma unroll
      for (int off = 1; off < 16; off <<= 1)
        mx = fmaxf(mx, __shfl_xor(mx, off, 64));
      const float mnew = fmaxf(m_i[r], mx);
      alpha[r] = __expf(m_i[r] - mnew);
      const int mrow = quad * 4 + r;
      float rs = 0.f;
#pragma unroll
      for (int nt = 0; nt < 8; ++nt) {
        const float p = __expf(S[nt][r] - mnew);
        rs += p;
        const int pg = ((nt * 2 + (col >> 3)) ^ mrow) & 15;
        pbuf[w][mrow * 128 + pg * 8 + (col & 7)] = (bf16_t)p;
      }
#pragma unroll
      for (int off = 1; off < 16; off <<= 1)
        rs += __shfl_xor(rs, off, 64);
      l_i[r] = l_i[r] * alpha[r] + rs;
      m_i[r] = mnew;
    }
#pragma unroll
    for (int dt = 0; dt < 8; ++dt)
#pragma unroll
      for (int r = 0; r < 4; ++r)
        O[dt][r] *= alpha[r];
    // P (A-layout via swizzled pbuf) @ V
#pragma unroll
    for (int kb = 0; kb < 4; ++kb) {
      const int pg = ((kb * 4 + quad) ^ col) & 15;
      const bf16x8 pa = *(const bf16x8*)(&pbuf[w][col * 128 + pg * 8]);
      const long srow = s0 + kb * 32 + quad * 8;
#pragma unroll
      for (int dt = 0; dt < 8; ++dt) {
        const bf16x8 bv = *(const bf16x8*)(vt + (long)(hkvHD + dt * 16 + col) * T_SEQ + srow);
        O[dt] = __builtin_amdgcn_mfma_f32_16x16x32_bf16(pa, bv, O[dt], 0, 0, 0);
      }
    }
  }

#pragma unroll
  for (int r = 0; r < 4; ++r) l_i[r] = 1.f / l_i[r];
#pragma unroll
  for (int dt = 0; dt < 8; ++dt) {
#pragma unroll
    for (int r = 0; r < 4; ++r) {
      const long trow = t0 + quad * 4 + r;
      out[trow * os + h * HD + dt * 16 + col] = (bf16_t)(O[dt][r] * l_i[r]);
    }
  }
}

extern "C" void kernel_launch(void* const* d_in, const int* in_sizes, int n_in,
                              void* d_out_v, int out_size, void* d_ws, size_t ws_size,
                              hipStream_t stream) {
  const int* pos = (const int*)d_in[0];
  const float* hidden = (const float*)d_in[1];
  const float* wq = (const float*)d_in[2];
  const float* bq = (const float*)d_in[3];
  const float* wk = (const float*)d_in[4];
  const float* bk = (const float*)d_in[5];
  const float* wv = (const float*)d_in[6];
  const float* bv = (const float*)d_in[7];
  const float* wo = (const float*)d_in[8];

  bf16_t* qbuf = (bf16_t*)d_out_v;                          // lower half of d_out (bf16 q)
  bf16_t* attn_hi = (bf16_t*)d_out_v + (size_t)T_SEQ * HID; // upper half (fallback attn out)
  float* outf = (float*)d_out_v;

  char* ws = (char*)d_ws;
  const size_t NEED = 51904516;

  if (ws_size >= NEED) {
    // ---- fast path: pre-converted bf16 operands ----
    bf16_t* hbf  = (bf16_t*)ws;                  // [2048][3584]  (later: attn out)
    bf16_t* wqbf = (bf16_t*)(ws + 14680064);     // [3584][3584]  (later: wo bf16)
    bf16_t* wkbf = (bf16_t*)(ws + 40370176);     // [3584][512]
    bf16_t* wvbf = (bf16_t*)(ws + 44040192);     // [3584][512]
    bf16_t* kbuf = (bf16_t*)(ws + 47710208);     // [2048][512]
    bf16_t* vt   = (bf16_t*)(ws + 49807360);     // [512][2048]
    int* flag    = (int*)(ws + 51904512);
    bf16_t* wobf = wqbf;
    bf16_t* attnb = hbf;

    hipMemsetAsync(flag, 0, 4, stream);
    conv_bf_k<<<3584, 256, 0, stream>>>(hidden, hbf, (long)T_SEQ * HID);
    conv_bf_k<<<6272, 256, 0, stream>>>(wq, wqbf, (long)HID * HID);
    conv_bf_k<<<896, 256, 0, stream>>>(wk, wkbf, (long)HID * 512);
    conv_bf_k<<<896, 256, 0, stream>>>(wv, wvbf, (long)HID * 512);

    gemm_nt_k<<<dim3(28, 16), 256, 0, stream>>>(hbf, HID, wqbf, HID, bq, qbuf, HID,
                                                HID, 0, 0, 0, 0, flag);
    gemm_nt_k<<<dim3(4, 16), 256, 0, stream>>>(hbf, HID, wkbf, 512, bk, kbuf, 512,
                                               HID, 0, 0, 0, 0, flag);
    gemm_nt_k<<<dim3(4, 16), 256, 0, stream>>>(hbf, HID, wvbf, 512, bv, vt, T_SEQ,
                                               HID, 0, 0, 1, 0, flag);

    rope_k<<<(T_SEQ * NH * 64) / 256, 256, 0, stream>>>(qbuf, pos, HID, NH);
    rope_k<<<(T_SEQ * NKV * 64) / 256, 256, 0, stream>>>(kbuf, pos, 512, NKV);

    // attention: q (d_out lower) -> attnb (= hbf region, hidden now dead)
    attn2_k<<<dim3(32, 28), 256, 0, stream>>>(qbuf, HID, kbuf, 512, vt, attnb, HID);

    // wo -> bf16 (reuses wq region, dead after q-GEMM)
    conv_bf_k<<<6272, 256, 0, stream>>>(wo, wobf, (long)HID * HID);

    // out = attn @ wo, fp32, single launch (reads ws only, writes all of d_out)
    gemm_nt_k<<<dim3(28, 16), 256, 0, stream>>>(attnb, HID, wobf, HID, nullptr,
                                                outf, HID, HID, 0, 0, 0, 1, flag);
  } else {
    // ---- fallback: R5-proven fp32-reading path (ws >= 4,194,308) ----
    bf16_t* kbuf = (bf16_t*)ws;
    bf16_t* vt = (bf16_t*)(ws + 2097152);
    bf16_t* acopy = (bf16_t*)ws;
    int* flag = (int*)(ws + 4194304);

    hipMemsetAsync(flag, 64, 4, stream);  // 0x40404040 > 32 -> fp32 inputs

    gemm_nt_k<<<dim3(28, 16), 256, 0, stream>>>(hidden, HID, wq, HID, bq, qbuf, HID,
                                                HID, 1, 1, 0, 0, flag);
    gemm_nt_k<<<dim3(4, 16), 256, 0, stream>>>(hidden, HID, wk, 512, bk, kbuf, 512,
                                               HID, 1, 1, 0, 0, flag);
    gemm_nt_k<<<dim3(4, 16), 256, 0, stream>>>(hidden, HID, wv, 512, bv, vt, T_SEQ,
                                               HID, 1, 1, 1, 0, flag);

    rope_k<<<(T_SEQ * NH * 64) / 256, 256, 0, stream>>>(qbuf, pos, HID, NH);
    rope_k<<<(T_SEQ * NKV * 64) / 256, 256, 0, stream>>>(kbuf, pos, 512, NKV);

    attn2_k<<<dim3(32, 28), 256, 0, stream>>>(qbuf, HID, kbuf, 512, vt, attn_hi, HID);

    hipMemcpyAsync(acopy, attn_hi + (size_t)1536 * HID, (size_t)512 * HID * 2,
                   hipMemcpyDeviceToDevice, stream);
    gemm_nt_k<<<dim3(28, 8), 256, 0, stream>>>(attn_hi, HID, wo, HID, nullptr,
                                               outf, HID, HID, 0, 1, 0, 1, flag);
    gemm_nt_k<<<dim3(28, 4), 256, 0, stream>>>(attn_hi + (size_t)1024 * HID, HID, wo, HID,
                                               nullptr, outf + (size_t)1024 * HID, HID,
                                               HID, 0, 1, 0, 1, flag);
    gemm_nt_k<<<dim3(28, 4), 256, 0, stream>>>(acopy, HID, wo, HID,
                                               nullptr, outf + (size_t)1536 * HID, HID,
                                               HID, 0, 1, 0, 1, flag);
  }
}